// Round 9
// baseline (126.024 us; speedup 1.0000x reference)
//
#include <hip/hip_runtime.h>

// Swin-style attention: B=16, N=1024 (32x32), H=8, D=32, C=256.
// R8: projection GEMMs de-latencied. k_qkv/k_outproj build A-fragments
// DIRECTLY from global (no LDS, no barrier): x f32->bf16 via cvt_pk, aout is
// already fragment-contiguous bf16. Grids widened (qkv 256x6, outproj 256x4)
// for ~6 blocks/CU. k_attn: R7's 2-i-tile ILP version, unchanged.

using f32x4  = __attribute__((ext_vector_type(4))) float;
using bf16x8 = __attribute__((ext_vector_type(8))) short;

__device__ __forceinline__ short f2bf(float f) {
  union { float f; unsigned u; } v; v.f = f;
  return (short)((v.u + 0x7FFFu + ((v.u >> 16) & 1u)) >> 16);  // RNE
}
__device__ __forceinline__ f32x4 mfma_k32(bf16x8 a, bf16x8 b, f32x4 c) {
  return __builtin_amdgcn_mfma_f32_16x16x32_bf16(a, b, c, 0, 0, 0);
}
__device__ __forceinline__ int cvt_pk_bf16(float lo, float hi) {
  int r;
  asm("v_cvt_pk_bf16_f32 %0, %1, %2" : "=v"(r) : "v"(lo), "v"(hi));
  return r;
}

// ------- kernel 0: 4 weight transposes (bf16) + bias table prep, one launch ----
__global__ __launch_bounds__(256) void k_prep(const float* __restrict__ Wq,
    const float* __restrict__ Wk, const float* __restrict__ Wv,
    const float* __restrict__ Wo, short* __restrict__ WT,
    const float* __restrict__ bt, float* __restrict__ Tg) {
  int bx = blockIdx.x;
  if (bx < 1024) {
    int wid = bx >> 8, n = bx & 255, k = threadIdx.x;
    const float* W = wid == 0 ? Wq : wid == 1 ? Wk : wid == 2 ? Wv : Wo;
    WT[wid * 65536 + n * 256 + k] = f2bf(W[k * 256 + n]);
  } else {
    int idx = (bx - 1024) * 256 + threadIdx.x;  // 128 x 256 = 8 x 4096
    int h = idx >> 12, i = idx & 4095;
    if (i < 3969) Tg[idx] = bt[i * 8 + h] * 1.4426950408889634f;
  }
}

// ---------------- kernel 1: QKV projection, no LDS ----------------
// blockIdx.y: wi = y>>1 (Q/K/V), nt-half = y&1. Block = 64 rows x 128 cols.
// A-fragments straight from global x (f32 -> bf16 cvt_pk).
// V stored as fragment-ordered subtiles: Vf[((b*8+h)*32 + js)*1024 + d*32 + jp].
__global__ __launch_bounds__(256) void k_qkv(const float* __restrict__ x,
    const short* __restrict__ WT,
    short* __restrict__ Q, short* __restrict__ K, short* __restrict__ Vt) {
  const int tid = threadIdx.x;
  const int w = tid >> 6, l = tid & 63, lr = l & 15, lg = l >> 4;
  const int m0 = blockIdx.x * 64;
  const int wi = blockIdx.y >> 1;
  const int nt0 = (blockIdx.y & 1) * 8;
  const short* Wt = WT + wi * 65536;
  const float* xrow = x + (size_t)(m0 + w * 16 + lr) * 256;
  bf16x8 af[8];
  #pragma unroll
  for (int kc = 0; kc < 8; ++kc) {
    float4 a = *reinterpret_cast<const float4*>(xrow + kc * 32 + lg * 8);
    float4 c = *reinterpret_cast<const float4*>(xrow + kc * 32 + lg * 8 + 4);
    union { int i4[4]; bf16x8 v; } u;
    u.i4[0] = cvt_pk_bf16(a.x, a.y);
    u.i4[1] = cvt_pk_bf16(a.z, a.w);
    u.i4[2] = cvt_pk_bf16(c.x, c.y);
    u.i4[3] = cvt_pk_bf16(c.z, c.w);
    af[kc] = u.v;
  }
  #pragma unroll 4
  for (int nt = nt0; nt < nt0 + 8; ++nt) {
    f32x4 acc = {0.f, 0.f, 0.f, 0.f};
    #pragma unroll
    for (int kc = 0; kc < 8; ++kc) {
      bf16x8 bfr = *reinterpret_cast<const bf16x8*>(
          &Wt[(nt * 16 + lr) * 256 + kc * 32 + lg * 8]);
      acc = mfma_k32(af[kc], bfr, acc);
    }
    int colb = nt * 16 + lr;
    int h = colb >> 5, d = colb & 31;
    if (wi == 2) {
      int m = m0 + w * 16 + lg * 4;  // 4 consecutive n (r=0..3)
      int b = m >> 10, n0 = m & 1023;
      int js = n0 >> 5;
      int lgv = (n0 & 15) >> 2, hi = (n0 >> 4) & 1;
      int jp = lgv * 8 + hi * 4;
      short4 vv;
      vv.x = f2bf(acc[0]); vv.y = f2bf(acc[1]);
      vv.z = f2bf(acc[2]); vv.w = f2bf(acc[3]);
      *reinterpret_cast<short4*>(
          &Vt[(((size_t)(b * 8 + h) * 32 + js) << 10) + d * 32 + jp]) = vv;
    } else {
      #pragma unroll
      for (int r = 0; r < 4; ++r) {
        int m = m0 + w * 16 + lg * 4 + r;
        int b = m >> 10, n = m & 1023;
        short val = f2bf(acc[r]);
        if (wi == 0)
          Q[((size_t)(b * 8 + h) * 1024 + n) * 32 + d] = val;
        else
          K[((size_t)(b * 8 + h) * 1024 + n) * 32 + d] = val;
      }
    }
  }
}

// ---------------- kernel 2: flash attention, 2 i-tiles per wave (R7) ----------
__global__ __launch_bounds__(256) void k_attn(const short* __restrict__ Q,
    const short* __restrict__ K, const short* __restrict__ Vt,
    const float* __restrict__ Tg, short* __restrict__ aout) {
  __shared__ float Tlds[3969];  // per-head 63x63 bias table (x log2e)
  const int tid = threadIdx.x, bid = blockIdx.x;
  const int h = bid & 7, qt = (bid >> 3) & 7, b = bid >> 6;
  const float* Th = Tg + (h << 12);
  for (int t = tid; t < 3969; t += 256) Tlds[t] = Th[t];
  __syncthreads();
  const int w = tid >> 6, l = tid & 63, lr = l & 15, lg = l >> 4;
  const size_t hoff = (size_t)(b * 8 + h) << 15;
  const short* Qh = Q + hoff;
  const short* Kh = K + hoff;
  const short* Vh = Vt + hoff;
  const int ita = qt * 4 + w;          // 0..31
  const int i0a = ita * 16;            // rows 0..511
  const int i0b = i0a + 512;           // rows 512..1023 (same x-parity)
  const int yia = ita >> 1;
  const int pbase = ((ita & 1) << 4) + lr - lg * 4 + 31;
  bf16x8 qfa = *reinterpret_cast<const bf16x8*>(&Qh[(i0a + lr) * 32 + lg * 8]);
  bf16x8 qfb = *reinterpret_cast<const bf16x8*>(&Qh[(i0b + lr) * 32 + lg * 8]);
  f32x4 oa0 = {0.f,0.f,0.f,0.f}, oa1 = {0.f,0.f,0.f,0.f};
  f32x4 ob0 = {0.f,0.f,0.f,0.f}, ob1 = {0.f,0.f,0.f,0.f};
  float lsa = 0.f, lsb = 0.f;
  const float cs = 0.17677669529663688f * 1.4426950408889634f;  // scale*log2e
  const int koff0 = lr * 32 + lg * 8, koff1 = (16 + lr) * 32 + lg * 8;
  bf16x8 kf0 = *reinterpret_cast<const bf16x8*>(&Kh[koff0]);
  bf16x8 kf1 = *reinterpret_cast<const bf16x8*>(&Kh[koff1]);
  bf16x8 vf0 = *reinterpret_cast<const bf16x8*>(&Vh[koff0]);
  bf16x8 vf1 = *reinterpret_cast<const bf16x8*>(&Vh[koff1]);
  #pragma unroll 2
  for (int js = 0; js < 32; ++js) {
    const int jn = (js + 1) & 31;  // js=31 reloads js=0, unused
    bf16x8 nkf0 = *reinterpret_cast<const bf16x8*>(&Kh[(jn << 10) + koff0]);
    bf16x8 nkf1 = *reinterpret_cast<const bf16x8*>(&Kh[(jn << 10) + koff1]);
    bf16x8 nvf0 = *reinterpret_cast<const bf16x8*>(&Vh[(jn << 10) + koff0]);
    bf16x8 nvf1 = *reinterpret_cast<const bf16x8*>(&Vh[(jn << 10) + koff1]);
    f32x4 z = {0.f, 0.f, 0.f, 0.f};
    f32x4 sa0 = mfma_k32(kf0, qfa, z);  // S[i0a+lr][j0+lg*4+r]
    f32x4 sa1 = mfma_k32(kf1, qfa, z);  // S[i0a+lr][j0+16+lg*4+r]
    f32x4 sb0 = mfma_k32(kf0, qfb, z);
    f32x4 sb1 = mfma_k32(kf1, qfb, z);
    const float* TrowA = &Tlds[(yia - js + 31) * 63];
    const float* TrowB = TrowA + 16 * 63;  // yib = yia + 16
    float pa0[4], pa1[4], pb0[4], pb1[4];
    #pragma unroll
    for (int r = 0; r < 4; ++r) {
      pa0[r] = __builtin_amdgcn_exp2f(fmaf(sa0[r], cs, TrowA[pbase - r]));
      pa1[r] = __builtin_amdgcn_exp2f(fmaf(sa1[r], cs, TrowA[pbase - 16 - r]));
      pb0[r] = __builtin_amdgcn_exp2f(fmaf(sb0[r], cs, TrowB[pbase - r]));
      pb1[r] = __builtin_amdgcn_exp2f(fmaf(sb1[r], cs, TrowB[pbase - 16 - r]));
      lsa += pa0[r] + pa1[r];
      lsb += pb0[r] + pb1[r];
    }
    union { int i4[4]; bf16x8 v; } pka, pkb;
    pka.i4[0] = cvt_pk_bf16(pa0[0], pa0[1]);
    pka.i4[1] = cvt_pk_bf16(pa0[2], pa0[3]);
    pka.i4[2] = cvt_pk_bf16(pa1[0], pa1[1]);
    pka.i4[3] = cvt_pk_bf16(pa1[2], pa1[3]);
    pkb.i4[0] = cvt_pk_bf16(pb0[0], pb0[1]);
    pkb.i4[1] = cvt_pk_bf16(pb0[2], pb0[3]);
    pkb.i4[2] = cvt_pk_bf16(pb1[0], pb1[1]);
    pkb.i4[3] = cvt_pk_bf16(pb1[2], pb1[3]);
    oa0 = mfma_k32(pka.v, vf0, oa0);  // O[i0a+lg*4+r][d=lr]
    oa1 = mfma_k32(pka.v, vf1, oa1);  // O[i0a+..][d=16+lr]
    ob0 = mfma_k32(pkb.v, vf0, ob0);
    ob1 = mfma_k32(pkb.v, vf1, ob1);
    kf0 = nkf0; kf1 = nkf1; vf0 = nvf0; vf1 = nvf1;
  }
  {
    float s = lsa + __shfl_xor(lsa, 16);
    s += __shfl_xor(s, 32);
    float inv = 1.0f / s;
    #pragma unroll
    for (int r = 0; r < 4; ++r) {
      float invr = __shfl(inv, lg * 4 + r);
      int n = i0a + lg * 4 + r;
      size_t base = ((size_t)b << 18) + (size_t)n * 256 + h * 32;
      aout[base + lr]      = f2bf(oa0[r] * invr);
      aout[base + 16 + lr] = f2bf(oa1[r] * invr);
    }
  }
  {
    float s = lsb + __shfl_xor(lsb, 16);
    s += __shfl_xor(s, 32);
    float inv = 1.0f / s;
    #pragma unroll
    for (int r = 0; r < 4; ++r) {
      float invr = __shfl(inv, lg * 4 + r);
      int n = i0b + lg * 4 + r;
      size_t base = ((size_t)b << 18) + (size_t)n * 256 + h * 32;
      aout[base + lr]      = f2bf(ob0[r] * invr);
      aout[base + 16 + lr] = f2bf(ob1[r] * invr);
    }
  }
}

// ---------------- kernel 3: output projection, no LDS ----------------
// aout is bf16 and fragment-contiguous: direct 16B A-loads, no staging.
// Grid dim3(256, 4): 64 rows x 64 cols per block.
__global__ __launch_bounds__(256) void k_outproj(const short* __restrict__ aout,
    const short* __restrict__ WoT, const float* __restrict__ bo,
    float* __restrict__ out) {
  const int tid = threadIdx.x;
  const int w = tid >> 6, l = tid & 63, lr = l & 15, lg = l >> 4;
  const int m0 = blockIdx.x * 64;
  const int nt0 = blockIdx.y * 4;
  const short* arow = aout + (size_t)(m0 + w * 16 + lr) * 256;
  bf16x8 af[8];
  #pragma unroll
  for (int kc = 0; kc < 8; ++kc)
    af[kc] = *reinterpret_cast<const bf16x8*>(arow + kc * 32 + lg * 8);
  #pragma unroll
  for (int nt = nt0; nt < nt0 + 4; ++nt) {
    f32x4 acc = {0.f, 0.f, 0.f, 0.f};
    #pragma unroll
    for (int kc = 0; kc < 8; ++kc) {
      bf16x8 bfr = *reinterpret_cast<const bf16x8*>(
          &WoT[(nt * 16 + lr) * 256 + kc * 32 + lg * 8]);
      acc = mfma_k32(af[kc], bfr, acc);
    }
    int colb = nt * 16 + lr;
    float bias = bo[colb];
    #pragma unroll
    for (int r = 0; r < 4; ++r) {
      int m = m0 + w * 16 + lg * 4 + r;
      out[(size_t)m * 256 + colb] = acc[r] + bias;
    }
  }
}

extern "C" void kernel_launch(void* const* d_in, const int* in_sizes, int n_in,
                              void* d_out, int out_size, void* d_ws, size_t ws_size,
                              hipStream_t stream) {
  const float* x  = (const float*)d_in[0];
  const float* Wq = (const float*)d_in[1];
  const float* Wk = (const float*)d_in[2];
  const float* Wv = (const float*)d_in[3];
  const float* bt = (const float*)d_in[4];
  const float* Wo = (const float*)d_in[5];
  const float* bo = (const float*)d_in[6];
  float* out = (float*)d_out;
  char* ws = (char*)d_ws;
  short* WT   = (short*)ws;                          // 4 x 65536 shorts = 512 KB
  short* Qs   = (short*)(ws + 512 * 1024);           // 8 MB each
  short* Ks   = Qs + 4194304;
  short* Vts  = Ks + 4194304;
  short* aout = Vts + 4194304;
  float* Tg   = (float*)(ws + 512 * 1024 + 4ull * 8388608);  // 8x4096 f32 = 128 KB

  k_prep<<<1152, 256, 0, stream>>>(Wq, Wk, Wv, Wo, WT, bt, Tg);
  k_qkv<<<dim3(256, 6), 256, 0, stream>>>(x, WT, Qs, Ks, Vts);
  k_attn<<<1024, 256, 0, stream>>>(Qs, Ks, Vts, Tg, aout);
  k_outproj<<<dim3(256, 4), 256, 0, stream>>>(aout, WT + 3 * 65536, bo, out);
}

// Round 10
// 80.369 us; speedup vs baseline: 1.5681x; 1.5681x over previous
//
#include <hip/hip_runtime.h>

// Swin-style attention: B=16, N=1024 (32x32), H=8, D=32, C=256.
// R9: projection GEMMs restructured: W staged through double-buffered LDS
// (8KB nt-tiles, XOR-swizzled to kill ds_read_b128 bank conflicts), A-frags
// direct from global. Fixes the W-from-L2 latency stall that kept k_qkv at
// 3.8% MfmaUtil. k_attn: R7 2-i-tile ILP version, unchanged.

using f32x4  = __attribute__((ext_vector_type(4))) float;
using bf16x8 = __attribute__((ext_vector_type(8))) short;

__device__ __forceinline__ short f2bf(float f) {
  union { float f; unsigned u; } v; v.f = f;
  return (short)((v.u + 0x7FFFu + ((v.u >> 16) & 1u)) >> 16);  // RNE
}
__device__ __forceinline__ f32x4 mfma_k32(bf16x8 a, bf16x8 b, f32x4 c) {
  return __builtin_amdgcn_mfma_f32_16x16x32_bf16(a, b, c, 0, 0, 0);
}
__device__ __forceinline__ int cvt_pk_bf16(float lo, float hi) {
  int r;
  asm("v_cvt_pk_bf16_f32 %0, %1, %2" : "=v"(r) : "v"(lo), "v"(hi));
  return r;
}

// ------- kernel 0: 4 weight transposes (bf16) + bias table prep, one launch ----
__global__ __launch_bounds__(256) void k_prep(const float* __restrict__ Wq,
    const float* __restrict__ Wk, const float* __restrict__ Wv,
    const float* __restrict__ Wo, short* __restrict__ WT,
    const float* __restrict__ bt, float* __restrict__ Tg) {
  int bx = blockIdx.x;
  if (bx < 1024) {
    int wid = bx >> 8, n = bx & 255, k = threadIdx.x;
    const float* W = wid == 0 ? Wq : wid == 1 ? Wk : wid == 2 ? Wv : Wo;
    WT[wid * 65536 + n * 256 + k] = f2bf(W[k * 256 + n]);
  } else {
    int idx = (bx - 1024) * 256 + threadIdx.x;  // 128 x 256 = 8 x 4096
    int h = idx >> 12, i = idx & 4095;
    if (i < 3969) Tg[idx] = bt[i * 8 + h] * 1.4426950408889634f;
  }
}

// ---------------- kernel 1: QKV projection, W via dbuf LDS ----------------
// Block = 64 rows x 256 cols, wi = blockIdx.y. Loop nt: stage next 8KB W-tile
// (16 cols x 256 k) while computing current from swizzled LDS.
// V stored as fragment-ordered subtiles: Vf[((b*8+h)*32 + js)*1024 + d*32 + jp].
__global__ __launch_bounds__(256) void k_qkv(const float* __restrict__ x,
    const short* __restrict__ WT,
    short* __restrict__ Q, short* __restrict__ K, short* __restrict__ Vt) {
  __shared__ short Wlds[2][4096];  // 2 x 8KB
  char* lbase = (char*)Wlds;
  const int tid = threadIdx.x;
  const int w = tid >> 6, l = tid & 63, lr = l & 15, lg = l >> 4;
  const int m0 = blockIdx.x * 64;
  const int wi = blockIdx.y;
  const char* Wb = (const char*)(WT + wi * 65536);  // wi weight, bytes
  // A-fragments direct from global x (f32 -> bf16 cvt_pk), hoisted
  const float* xrow = x + (size_t)(m0 + w * 16 + lr) * 256;
  bf16x8 af[8];
  #pragma unroll
  for (int kc = 0; kc < 8; ++kc) {
    float4 a = *reinterpret_cast<const float4*>(xrow + kc * 32 + lg * 8);
    float4 c = *reinterpret_cast<const float4*>(xrow + kc * 32 + lg * 8 + 4);
    union { int i4[4]; bf16x8 v; } u;
    u.i4[0] = cvt_pk_bf16(a.x, a.y);
    u.i4[1] = cvt_pk_bf16(a.z, a.w);
    u.i4[2] = cvt_pk_bf16(c.x, c.y);
    u.i4[3] = cvt_pk_bf16(c.z, c.w);
    af[kc] = u.v;
  }
  // stager geometry: logical byte L in 8KB tile (row = L>>9, 512B rows);
  // physical LDS byte = L ^ ((row&7)<<4)  [T2 swizzle, both sides]
  const int Lb0 = tid * 16, Lb1 = 4096 + tid * 16;
  const int P0 = Lb0 ^ (((Lb0 >> 9) & 7) << 4);
  const int P1 = Lb1 ^ (((Lb1 >> 9) & 7) << 4);
  // reader offsets: logical Lg = lr*512 + kc*64 + lg*16, phys = Lg^((lr&7)<<4)
  int rdo[8];
  #pragma unroll
  for (int kc = 0; kc < 8; ++kc) {
    int Lg = lr * 512 + kc * 64 + lg * 16;
    rdo[kc] = Lg ^ ((lr & 7) << 4);
  }
  // prologue: stage nt=0 into buf 0
  {
    int4 s0 = *reinterpret_cast<const int4*>(Wb + Lb0);
    int4 s1 = *reinterpret_cast<const int4*>(Wb + Lb1);
    *reinterpret_cast<int4*>(lbase + P0) = s0;
    *reinterpret_cast<int4*>(lbase + P1) = s1;
  }
  __syncthreads();
  #pragma unroll 2
  for (int nt = 0; nt < 16; ++nt) {
    const int cur = nt & 1, nxt = cur ^ 1;
    int4 t0, t1;
    if (nt < 15) {  // issue next tile's loads early (latency hides under MFMA)
      t0 = *reinterpret_cast<const int4*>(Wb + (nt + 1) * 8192 + Lb0);
      t1 = *reinterpret_cast<const int4*>(Wb + (nt + 1) * 8192 + Lb1);
    }
    f32x4 acc = {0.f, 0.f, 0.f, 0.f};
    #pragma unroll
    for (int kc = 0; kc < 8; ++kc) {
      bf16x8 bfr = *reinterpret_cast<const bf16x8*>(lbase + cur * 8192 + rdo[kc]);
      acc = mfma_k32(af[kc], bfr, acc);
    }
    int colb = nt * 16 + lr;
    int h = colb >> 5, d = colb & 31;
    if (wi == 2) {
      int m = m0 + w * 16 + lg * 4;  // 4 consecutive n (r=0..3)
      int b = m >> 10, n0 = m & 1023;
      int js = n0 >> 5;
      int lgv = (n0 & 15) >> 2, hi = (n0 >> 4) & 1;
      int jp = lgv * 8 + hi * 4;
      short4 vv;
      vv.x = f2bf(acc[0]); vv.y = f2bf(acc[1]);
      vv.z = f2bf(acc[2]); vv.w = f2bf(acc[3]);
      *reinterpret_cast<short4*>(
          &Vt[(((size_t)(b * 8 + h) * 32 + js) << 10) + d * 32 + jp]) = vv;
    } else {
      #pragma unroll
      for (int r = 0; r < 4; ++r) {
        int m = m0 + w * 16 + lg * 4 + r;
        int b = m >> 10, n = m & 1023;
        short val = f2bf(acc[r]);
        if (wi == 0)
          Q[((size_t)(b * 8 + h) * 1024 + n) * 32 + d] = val;
        else
          K[((size_t)(b * 8 + h) * 1024 + n) * 32 + d] = val;
      }
    }
    if (nt < 15) {  // write next tile; safe: buf[nxt] not read this iter
      *reinterpret_cast<int4*>(lbase + nxt * 8192 + P0) = t0;
      *reinterpret_cast<int4*>(lbase + nxt * 8192 + P1) = t1;
    }
    __syncthreads();
  }
}

// ---------------- kernel 2: flash attention, 2 i-tiles per wave (R7) ----------
__global__ __launch_bounds__(256) void k_attn(const short* __restrict__ Q,
    const short* __restrict__ K, const short* __restrict__ Vt,
    const float* __restrict__ Tg, short* __restrict__ aout) {
  __shared__ float Tlds[3969];  // per-head 63x63 bias table (x log2e)
  const int tid = threadIdx.x, bid = blockIdx.x;
  const int h = bid & 7, qt = (bid >> 3) & 7, b = bid >> 6;
  const float* Th = Tg + (h << 12);
  for (int t = tid; t < 3969; t += 256) Tlds[t] = Th[t];
  __syncthreads();
  const int w = tid >> 6, l = tid & 63, lr = l & 15, lg = l >> 4;
  const size_t hoff = (size_t)(b * 8 + h) << 15;
  const short* Qh = Q + hoff;
  const short* Kh = K + hoff;
  const short* Vh = Vt + hoff;
  const int ita = qt * 4 + w;          // 0..31
  const int i0a = ita * 16;            // rows 0..511
  const int i0b = i0a + 512;           // rows 512..1023 (same x-parity)
  const int yia = ita >> 1;
  const int pbase = ((ita & 1) << 4) + lr - lg * 4 + 31;
  bf16x8 qfa = *reinterpret_cast<const bf16x8*>(&Qh[(i0a + lr) * 32 + lg * 8]);
  bf16x8 qfb = *reinterpret_cast<const bf16x8*>(&Qh[(i0b + lr) * 32 + lg * 8]);
  f32x4 oa0 = {0.f,0.f,0.f,0.f}, oa1 = {0.f,0.f,0.f,0.f};
  f32x4 ob0 = {0.f,0.f,0.f,0.f}, ob1 = {0.f,0.f,0.f,0.f};
  float lsa = 0.f, lsb = 0.f;
  const float cs = 0.17677669529663688f * 1.4426950408889634f;  // scale*log2e
  const int koff0 = lr * 32 + lg * 8, koff1 = (16 + lr) * 32 + lg * 8;
  bf16x8 kf0 = *reinterpret_cast<const bf16x8*>(&Kh[koff0]);
  bf16x8 kf1 = *reinterpret_cast<const bf16x8*>(&Kh[koff1]);
  bf16x8 vf0 = *reinterpret_cast<const bf16x8*>(&Vh[koff0]);
  bf16x8 vf1 = *reinterpret_cast<const bf16x8*>(&Vh[koff1]);
  #pragma unroll 2
  for (int js = 0; js < 32; ++js) {
    const int jn = (js + 1) & 31;  // js=31 reloads js=0, unused
    bf16x8 nkf0 = *reinterpret_cast<const bf16x8*>(&Kh[(jn << 10) + koff0]);
    bf16x8 nkf1 = *reinterpret_cast<const bf16x8*>(&Kh[(jn << 10) + koff1]);
    bf16x8 nvf0 = *reinterpret_cast<const bf16x8*>(&Vh[(jn << 10) + koff0]);
    bf16x8 nvf1 = *reinterpret_cast<const bf16x8*>(&Vh[(jn << 10) + koff1]);
    f32x4 z = {0.f, 0.f, 0.f, 0.f};
    f32x4 sa0 = mfma_k32(kf0, qfa, z);  // S[i0a+lr][j0+lg*4+r]
    f32x4 sa1 = mfma_k32(kf1, qfa, z);  // S[i0a+lr][j0+16+lg*4+r]
    f32x4 sb0 = mfma_k32(kf0, qfb, z);
    f32x4 sb1 = mfma_k32(kf1, qfb, z);
    const float* TrowA = &Tlds[(yia - js + 31) * 63];
    const float* TrowB = TrowA + 16 * 63;  // yib = yia + 16
    float pa0[4], pa1[4], pb0[4], pb1[4];
    #pragma unroll
    for (int r = 0; r < 4; ++r) {
      pa0[r] = __builtin_amdgcn_exp2f(fmaf(sa0[r], cs, TrowA[pbase - r]));
      pa1[r] = __builtin_amdgcn_exp2f(fmaf(sa1[r], cs, TrowA[pbase - 16 - r]));
      pb0[r] = __builtin_amdgcn_exp2f(fmaf(sb0[r], cs, TrowB[pbase - r]));
      pb1[r] = __builtin_amdgcn_exp2f(fmaf(sb1[r], cs, TrowB[pbase - 16 - r]));
      lsa += pa0[r] + pa1[r];
      lsb += pb0[r] + pb1[r];
    }
    union { int i4[4]; bf16x8 v; } pka, pkb;
    pka.i4[0] = cvt_pk_bf16(pa0[0], pa0[1]);
    pka.i4[1] = cvt_pk_bf16(pa0[2], pa0[3]);
    pka.i4[2] = cvt_pk_bf16(pa1[0], pa1[1]);
    pka.i4[3] = cvt_pk_bf16(pa1[2], pa1[3]);
    pkb.i4[0] = cvt_pk_bf16(pb0[0], pb0[1]);
    pkb.i4[1] = cvt_pk_bf16(pb0[2], pb0[3]);
    pkb.i4[2] = cvt_pk_bf16(pb1[0], pb1[1]);
    pkb.i4[3] = cvt_pk_bf16(pb1[2], pb1[3]);
    oa0 = mfma_k32(pka.v, vf0, oa0);  // O[i0a+lg*4+r][d=lr]
    oa1 = mfma_k32(pka.v, vf1, oa1);  // O[i0a+..][d=16+lr]
    ob0 = mfma_k32(pkb.v, vf0, ob0);
    ob1 = mfma_k32(pkb.v, vf1, ob1);
    kf0 = nkf0; kf1 = nkf1; vf0 = nvf0; vf1 = nvf1;
  }
  {
    float s = lsa + __shfl_xor(lsa, 16);
    s += __shfl_xor(s, 32);
    float inv = 1.0f / s;
    #pragma unroll
    for (int r = 0; r < 4; ++r) {
      float invr = __shfl(inv, lg * 4 + r);
      int n = i0a + lg * 4 + r;
      size_t base = ((size_t)b << 18) + (size_t)n * 256 + h * 32;
      aout[base + lr]      = f2bf(oa0[r] * invr);
      aout[base + 16 + lr] = f2bf(oa1[r] * invr);
    }
  }
  {
    float s = lsb + __shfl_xor(lsb, 16);
    s += __shfl_xor(s, 32);
    float inv = 1.0f / s;
    #pragma unroll
    for (int r = 0; r < 4; ++r) {
      float invr = __shfl(inv, lg * 4 + r);
      int n = i0b + lg * 4 + r;
      size_t base = ((size_t)b << 18) + (size_t)n * 256 + h * 32;
      aout[base + lr]      = f2bf(ob0[r] * invr);
      aout[base + 16 + lr] = f2bf(ob1[r] * invr);
    }
  }
}

// ---------------- kernel 3: output projection, W via dbuf LDS ----------------
// aout is bf16 fragment-contiguous: direct 16B A-loads. Same W staging as qkv.
__global__ __launch_bounds__(256) void k_outproj(const short* __restrict__ aout,
    const short* __restrict__ WoT, const float* __restrict__ bo,
    float* __restrict__ out) {
  __shared__ short Wlds[2][4096];
  char* lbase = (char*)Wlds;
  const int tid = threadIdx.x;
  const int w = tid >> 6, l = tid & 63, lr = l & 15, lg = l >> 4;
  const int m0 = blockIdx.x * 64;
  const char* Wb = (const char*)WoT;
  const short* arow = aout + (size_t)(m0 + w * 16 + lr) * 256;
  bf16x8 af[8];
  #pragma unroll
  for (int kc = 0; kc < 8; ++kc)
    af[kc] = *reinterpret_cast<const bf16x8*>(arow + kc * 32 + lg * 8);
  const int Lb0 = tid * 16, Lb1 = 4096 + tid * 16;
  const int P0 = Lb0 ^ (((Lb0 >> 9) & 7) << 4);
  const int P1 = Lb1 ^ (((Lb1 >> 9) & 7) << 4);
  int rdo[8];
  #pragma unroll
  for (int kc = 0; kc < 8; ++kc) {
    int Lg = lr * 512 + kc * 64 + lg * 16;
    rdo[kc] = Lg ^ ((lr & 7) << 4);
  }
  {
    int4 s0 = *reinterpret_cast<const int4*>(Wb + Lb0);
    int4 s1 = *reinterpret_cast<const int4*>(Wb + Lb1);
    *reinterpret_cast<int4*>(lbase + P0) = s0;
    *reinterpret_cast<int4*>(lbase + P1) = s1;
  }
  __syncthreads();
  #pragma unroll 2
  for (int nt = 0; nt < 16; ++nt) {
    const int cur = nt & 1, nxt = cur ^ 1;
    int4 t0, t1;
    if (nt < 15) {
      t0 = *reinterpret_cast<const int4*>(Wb + (nt + 1) * 8192 + Lb0);
      t1 = *reinterpret_cast<const int4*>(Wb + (nt + 1) * 8192 + Lb1);
    }
    f32x4 acc = {0.f, 0.f, 0.f, 0.f};
    #pragma unroll
    for (int kc = 0; kc < 8; ++kc) {
      bf16x8 bfr = *reinterpret_cast<const bf16x8*>(lbase + cur * 8192 + rdo[kc]);
      acc = mfma_k32(af[kc], bfr, acc);
    }
    int colb = nt * 16 + lr;
    float bias = bo[colb];
    #pragma unroll
    for (int r = 0; r < 4; ++r) {
      int m = m0 + w * 16 + lg * 4 + r;
      out[(size_t)m * 256 + colb] = acc[r] + bias;
    }
    if (nt < 15) {
      *reinterpret_cast<int4*>(lbase + nxt * 8192 + P0) = t0;
      *reinterpret_cast<int4*>(lbase + nxt * 8192 + P1) = t1;
    }
    __syncthreads();
  }
}

extern "C" void kernel_launch(void* const* d_in, const int* in_sizes, int n_in,
                              void* d_out, int out_size, void* d_ws, size_t ws_size,
                              hipStream_t stream) {
  const float* x  = (const float*)d_in[0];
  const float* Wq = (const float*)d_in[1];
  const float* Wk = (const float*)d_in[2];
  const float* Wv = (const float*)d_in[3];
  const float* bt = (const float*)d_in[4];
  const float* Wo = (const float*)d_in[5];
  const float* bo = (const float*)d_in[6];
  float* out = (float*)d_out;
  char* ws = (char*)d_ws;
  short* WT   = (short*)ws;                          // 4 x 65536 shorts = 512 KB
  short* Qs   = (short*)(ws + 512 * 1024);           // 8 MB each
  short* Ks   = Qs + 4194304;
  short* Vts  = Ks + 4194304;
  short* aout = Vts + 4194304;
  float* Tg   = (float*)(ws + 512 * 1024 + 4ull * 8388608);  // 8x4096 f32 = 128 KB

  k_prep<<<1152, 256, 0, stream>>>(Wq, Wk, Wv, Wo, WT, bt, Tg);
  k_qkv<<<dim3(256, 3), 256, 0, stream>>>(x, WT, Qs, Ks, Vts);
  k_attn<<<1024, 256, 0, stream>>>(Qs, Ks, Vts, Tg, aout);
  k_outproj<<<256, 256, 0, stream>>>(aout, WT + 3 * 65536, bo, out);
}

// Round 11
// 78.961 us; speedup vs baseline: 1.5960x; 1.0178x over previous
//
#include <hip/hip_runtime.h>

// Swin-style attention: B=16, N=1024 (32x32), H=8, D=32, C=256.
// R10: k_attn blocks widened to 8 waves with an in-block j-split (waves 0-3:
// js 0-15, waves 4-7: js 16-31, same i-tiles). No-max softmax partials merge
// linearly through LDS -> 32 waves/CU (2x occupancy) with no global roundtrip.
// Projections: R9 W-through-dbuf-LDS (unchanged).

using f32x4  = __attribute__((ext_vector_type(4))) float;
using bf16x8 = __attribute__((ext_vector_type(8))) short;

__device__ __forceinline__ short f2bf(float f) {
  union { float f; unsigned u; } v; v.f = f;
  return (short)((v.u + 0x7FFFu + ((v.u >> 16) & 1u)) >> 16);  // RNE
}
__device__ __forceinline__ f32x4 mfma_k32(bf16x8 a, bf16x8 b, f32x4 c) {
  return __builtin_amdgcn_mfma_f32_16x16x32_bf16(a, b, c, 0, 0, 0);
}
__device__ __forceinline__ int cvt_pk_bf16(float lo, float hi) {
  int r;
  asm("v_cvt_pk_bf16_f32 %0, %1, %2" : "=v"(r) : "v"(lo), "v"(hi));
  return r;
}

// ------- kernel 0: 4 weight transposes (bf16) + bias table prep, one launch ----
__global__ __launch_bounds__(256) void k_prep(const float* __restrict__ Wq,
    const float* __restrict__ Wk, const float* __restrict__ Wv,
    const float* __restrict__ Wo, short* __restrict__ WT,
    const float* __restrict__ bt, float* __restrict__ Tg) {
  int bx = blockIdx.x;
  if (bx < 1024) {
    int wid = bx >> 8, n = bx & 255, k = threadIdx.x;
    const float* W = wid == 0 ? Wq : wid == 1 ? Wk : wid == 2 ? Wv : Wo;
    WT[wid * 65536 + n * 256 + k] = f2bf(W[k * 256 + n]);
  } else {
    int idx = (bx - 1024) * 256 + threadIdx.x;  // 128 x 256 = 8 x 4096
    int h = idx >> 12, i = idx & 4095;
    if (i < 3969) Tg[idx] = bt[i * 8 + h] * 1.4426950408889634f;
  }
}

// ---------------- kernel 1: QKV projection, W via dbuf LDS (R9) ----------------
__global__ __launch_bounds__(256) void k_qkv(const float* __restrict__ x,
    const short* __restrict__ WT,
    short* __restrict__ Q, short* __restrict__ K, short* __restrict__ Vt) {
  __shared__ short Wlds[2][4096];  // 2 x 8KB
  char* lbase = (char*)Wlds;
  const int tid = threadIdx.x;
  const int w = tid >> 6, l = tid & 63, lr = l & 15, lg = l >> 4;
  const int m0 = blockIdx.x * 64;
  const int wi = blockIdx.y;
  const char* Wb = (const char*)(WT + wi * 65536);
  const float* xrow = x + (size_t)(m0 + w * 16 + lr) * 256;
  bf16x8 af[8];
  #pragma unroll
  for (int kc = 0; kc < 8; ++kc) {
    float4 a = *reinterpret_cast<const float4*>(xrow + kc * 32 + lg * 8);
    float4 c = *reinterpret_cast<const float4*>(xrow + kc * 32 + lg * 8 + 4);
    union { int i4[4]; bf16x8 v; } u;
    u.i4[0] = cvt_pk_bf16(a.x, a.y);
    u.i4[1] = cvt_pk_bf16(a.z, a.w);
    u.i4[2] = cvt_pk_bf16(c.x, c.y);
    u.i4[3] = cvt_pk_bf16(c.z, c.w);
    af[kc] = u.v;
  }
  const int Lb0 = tid * 16, Lb1 = 4096 + tid * 16;
  const int P0 = Lb0 ^ (((Lb0 >> 9) & 7) << 4);
  const int P1 = Lb1 ^ (((Lb1 >> 9) & 7) << 4);
  int rdo[8];
  #pragma unroll
  for (int kc = 0; kc < 8; ++kc) {
    int Lg = lr * 512 + kc * 64 + lg * 16;
    rdo[kc] = Lg ^ ((lr & 7) << 4);
  }
  {
    int4 s0 = *reinterpret_cast<const int4*>(Wb + Lb0);
    int4 s1 = *reinterpret_cast<const int4*>(Wb + Lb1);
    *reinterpret_cast<int4*>(lbase + P0) = s0;
    *reinterpret_cast<int4*>(lbase + P1) = s1;
  }
  __syncthreads();
  #pragma unroll 2
  for (int nt = 0; nt < 16; ++nt) {
    const int cur = nt & 1, nxt = cur ^ 1;
    int4 t0, t1;
    if (nt < 15) {
      t0 = *reinterpret_cast<const int4*>(Wb + (nt + 1) * 8192 + Lb0);
      t1 = *reinterpret_cast<const int4*>(Wb + (nt + 1) * 8192 + Lb1);
    }
    f32x4 acc = {0.f, 0.f, 0.f, 0.f};
    #pragma unroll
    for (int kc = 0; kc < 8; ++kc) {
      bf16x8 bfr = *reinterpret_cast<const bf16x8*>(lbase + cur * 8192 + rdo[kc]);
      acc = mfma_k32(af[kc], bfr, acc);
    }
    int colb = nt * 16 + lr;
    int h = colb >> 5, d = colb & 31;
    if (wi == 2) {
      int m = m0 + w * 16 + lg * 4;
      int b = m >> 10, n0 = m & 1023;
      int js = n0 >> 5;
      int lgv = (n0 & 15) >> 2, hi = (n0 >> 4) & 1;
      int jp = lgv * 8 + hi * 4;
      short4 vv;
      vv.x = f2bf(acc[0]); vv.y = f2bf(acc[1]);
      vv.z = f2bf(acc[2]); vv.w = f2bf(acc[3]);
      *reinterpret_cast<short4*>(
          &Vt[(((size_t)(b * 8 + h) * 32 + js) << 10) + d * 32 + jp]) = vv;
    } else {
      #pragma unroll
      for (int r = 0; r < 4; ++r) {
        int m = m0 + w * 16 + lg * 4 + r;
        int b = m >> 10, n = m & 1023;
        short val = f2bf(acc[r]);
        if (wi == 0)
          Q[((size_t)(b * 8 + h) * 1024 + n) * 32 + d] = val;
        else
          K[((size_t)(b * 8 + h) * 1024 + n) * 32 + d] = val;
      }
    }
    if (nt < 15) {
      *reinterpret_cast<int4*>(lbase + nxt * 8192 + P0) = t0;
      *reinterpret_cast<int4*>(lbase + nxt * 8192 + P1) = t1;
    }
    __syncthreads();
  }
}

// ------- kernel 2: flash attention, 8 waves, in-block j-split + LDS merge ------
// Block = (b, h, qt): waves 0-3 -> js 0..15, waves 4-7 -> js 16..31 of the
// same two i-tiles (rows i0a and i0a+512). Partials merge linearly (no-max
// softmax). Grid 1024, h in low bits.
__global__ __launch_bounds__(512) void k_attn(const short* __restrict__ Q,
    const short* __restrict__ K, const short* __restrict__ Vt,
    const float* __restrict__ Tg, short* __restrict__ aout) {
  __shared__ float Tlds[3969];        // per-head 63x63 bias table (x log2e)
  __shared__ float mO[4][4][4][64];   // [w][slot][r][lane] upper-half partials
  __shared__ float mls[4][2][64];     // [w][tile][lane]
  const int tid = threadIdx.x, bid = blockIdx.x;
  const int h = bid & 7, qt = (bid >> 3) & 7, b = bid >> 6;
  const float* Th = Tg + (h << 12);
  for (int t = tid; t < 3969; t += 512) Tlds[t] = Th[t];
  __syncthreads();
  const int wg = tid >> 6, l = tid & 63, lr = l & 15, lg = l >> 4;
  const int w = wg & 3, jh = wg >> 2;
  const size_t hoff = (size_t)(b * 8 + h) << 15;
  const short* Qh = Q + hoff;
  const short* Kh = K + hoff;
  const short* Vh = Vt + hoff;
  const int ita = qt * 4 + w;          // 0..31
  const int i0a = ita * 16;            // rows 0..511
  const int i0b = i0a + 512;           // rows 512..1023 (same x-parity)
  const int yia = ita >> 1;
  const int pbase = ((ita & 1) << 4) + lr - lg * 4 + 31;
  bf16x8 qfa = *reinterpret_cast<const bf16x8*>(&Qh[(i0a + lr) * 32 + lg * 8]);
  bf16x8 qfb = *reinterpret_cast<const bf16x8*>(&Qh[(i0b + lr) * 32 + lg * 8]);
  f32x4 oa0 = {0.f,0.f,0.f,0.f}, oa1 = {0.f,0.f,0.f,0.f};
  f32x4 ob0 = {0.f,0.f,0.f,0.f}, ob1 = {0.f,0.f,0.f,0.f};
  float lsa = 0.f, lsb = 0.f;
  const float cs = 0.17677669529663688f * 1.4426950408889634f;  // scale*log2e
  const int koff0 = lr * 32 + lg * 8, koff1 = (16 + lr) * 32 + lg * 8;
  const int js0 = jh * 16, jsE = js0 + 16;
  bf16x8 kf0 = *reinterpret_cast<const bf16x8*>(&Kh[(js0 << 10) + koff0]);
  bf16x8 kf1 = *reinterpret_cast<const bf16x8*>(&Kh[(js0 << 10) + koff1]);
  bf16x8 vf0 = *reinterpret_cast<const bf16x8*>(&Vh[(js0 << 10) + koff0]);
  bf16x8 vf1 = *reinterpret_cast<const bf16x8*>(&Vh[(js0 << 10) + koff1]);
  #pragma unroll 2
  for (int js = js0; js < jsE; ++js) {
    const int jn = (js + 1 < jsE) ? js + 1 : js;  // last iter: redundant reload
    bf16x8 nkf0 = *reinterpret_cast<const bf16x8*>(&Kh[(jn << 10) + koff0]);
    bf16x8 nkf1 = *reinterpret_cast<const bf16x8*>(&Kh[(jn << 10) + koff1]);
    bf16x8 nvf0 = *reinterpret_cast<const bf16x8*>(&Vh[(jn << 10) + koff0]);
    bf16x8 nvf1 = *reinterpret_cast<const bf16x8*>(&Vh[(jn << 10) + koff1]);
    f32x4 z = {0.f, 0.f, 0.f, 0.f};
    f32x4 sa0 = mfma_k32(kf0, qfa, z);  // S[i0a+lr][j0+lg*4+r]
    f32x4 sa1 = mfma_k32(kf1, qfa, z);  // S[i0a+lr][j0+16+lg*4+r]
    f32x4 sb0 = mfma_k32(kf0, qfb, z);
    f32x4 sb1 = mfma_k32(kf1, qfb, z);
    const float* TrowA = &Tlds[(yia - js + 31) * 63];
    const float* TrowB = TrowA + 16 * 63;  // yib = yia + 16
    float pa0[4], pa1[4], pb0[4], pb1[4];
    #pragma unroll
    for (int r = 0; r < 4; ++r) {
      pa0[r] = __builtin_amdgcn_exp2f(fmaf(sa0[r], cs, TrowA[pbase - r]));
      pa1[r] = __builtin_amdgcn_exp2f(fmaf(sa1[r], cs, TrowA[pbase - 16 - r]));
      pb0[r] = __builtin_amdgcn_exp2f(fmaf(sb0[r], cs, TrowB[pbase - r]));
      pb1[r] = __builtin_amdgcn_exp2f(fmaf(sb1[r], cs, TrowB[pbase - 16 - r]));
      lsa += pa0[r] + pa1[r];
      lsb += pb0[r] + pb1[r];
    }
    union { int i4[4]; bf16x8 v; } pka, pkb;
    pka.i4[0] = cvt_pk_bf16(pa0[0], pa0[1]);
    pka.i4[1] = cvt_pk_bf16(pa0[2], pa0[3]);
    pka.i4[2] = cvt_pk_bf16(pa1[0], pa1[1]);
    pka.i4[3] = cvt_pk_bf16(pa1[2], pa1[3]);
    pkb.i4[0] = cvt_pk_bf16(pb0[0], pb0[1]);
    pkb.i4[1] = cvt_pk_bf16(pb0[2], pb0[3]);
    pkb.i4[2] = cvt_pk_bf16(pb1[0], pb1[1]);
    pkb.i4[3] = cvt_pk_bf16(pb1[2], pb1[3]);
    oa0 = mfma_k32(pka.v, vf0, oa0);  // O[i0a+lg*4+r][d=lr]
    oa1 = mfma_k32(pka.v, vf1, oa1);  // O[i0a+..][d=16+lr]
    ob0 = mfma_k32(pkb.v, vf0, ob0);
    ob1 = mfma_k32(pkb.v, vf1, ob1);
    kf0 = nkf0; kf1 = nkf1; vf0 = nvf0; vf1 = nvf1;
  }
  // merge halves: upper waves publish partials, lower waves combine + store
  if (jh == 1) {
    #pragma unroll
    for (int r = 0; r < 4; ++r) {
      mO[w][0][r][l] = oa0[r];
      mO[w][1][r][l] = oa1[r];
      mO[w][2][r][l] = ob0[r];
      mO[w][3][r][l] = ob1[r];
    }
    mls[w][0][l] = lsa;
    mls[w][1][l] = lsb;
  }
  __syncthreads();
  if (jh == 0) {
    #pragma unroll
    for (int r = 0; r < 4; ++r) {
      oa0[r] += mO[w][0][r][l];
      oa1[r] += mO[w][1][r][l];
      ob0[r] += mO[w][2][r][l];
      ob1[r] += mO[w][3][r][l];
    }
    lsa += mls[w][0][l];
    lsb += mls[w][1][l];
    {
      float s = lsa + __shfl_xor(lsa, 16);
      s += __shfl_xor(s, 32);
      float inv = 1.0f / s;
      #pragma unroll
      for (int r = 0; r < 4; ++r) {
        float invr = __shfl(inv, lg * 4 + r);
        int n = i0a + lg * 4 + r;
        size_t base = ((size_t)b << 18) + (size_t)n * 256 + h * 32;
        aout[base + lr]      = f2bf(oa0[r] * invr);
        aout[base + 16 + lr] = f2bf(oa1[r] * invr);
      }
      s = lsb + __shfl_xor(lsb, 16);
      s += __shfl_xor(s, 32);
      inv = 1.0f / s;
      #pragma unroll
      for (int r = 0; r < 4; ++r) {
        float invr = __shfl(inv, lg * 4 + r);
        int n = i0b + lg * 4 + r;
        size_t base = ((size_t)b << 18) + (size_t)n * 256 + h * 32;
        aout[base + lr]      = f2bf(ob0[r] * invr);
        aout[base + 16 + lr] = f2bf(ob1[r] * invr);
      }
    }
  }
}

// ---------------- kernel 3: output projection, W via dbuf LDS (R9) -------------
__global__ __launch_bounds__(256) void k_outproj(const short* __restrict__ aout,
    const short* __restrict__ WoT, const float* __restrict__ bo,
    float* __restrict__ out) {
  __shared__ short Wlds[2][4096];
  char* lbase = (char*)Wlds;
  const int tid = threadIdx.x;
  const int w = tid >> 6, l = tid & 63, lr = l & 15, lg = l >> 4;
  const int m0 = blockIdx.x * 64;
  const char* Wb = (const char*)WoT;
  const short* arow = aout + (size_t)(m0 + w * 16 + lr) * 256;
  bf16x8 af[8];
  #pragma unroll
  for (int kc = 0; kc < 8; ++kc)
    af[kc] = *reinterpret_cast<const bf16x8*>(arow + kc * 32 + lg * 8);
  const int Lb0 = tid * 16, Lb1 = 4096 + tid * 16;
  const int P0 = Lb0 ^ (((Lb0 >> 9) & 7) << 4);
  const int P1 = Lb1 ^ (((Lb1 >> 9) & 7) << 4);
  int rdo[8];
  #pragma unroll
  for (int kc = 0; kc < 8; ++kc) {
    int Lg = lr * 512 + kc * 64 + lg * 16;
    rdo[kc] = Lg ^ ((lr & 7) << 4);
  }
  {
    int4 s0 = *reinterpret_cast<const int4*>(Wb + Lb0);
    int4 s1 = *reinterpret_cast<const int4*>(Wb + Lb1);
    *reinterpret_cast<int4*>(lbase + P0) = s0;
    *reinterpret_cast<int4*>(lbase + P1) = s1;
  }
  __syncthreads();
  #pragma unroll 2
  for (int nt = 0; nt < 16; ++nt) {
    const int cur = nt & 1, nxt = cur ^ 1;
    int4 t0, t1;
    if (nt < 15) {
      t0 = *reinterpret_cast<const int4*>(Wb + (nt + 1) * 8192 + Lb0);
      t1 = *reinterpret_cast<const int4*>(Wb + (nt + 1) * 8192 + Lb1);
    }
    f32x4 acc = {0.f, 0.f, 0.f, 0.f};
    #pragma unroll
    for (int kc = 0; kc < 8; ++kc) {
      bf16x8 bfr = *reinterpret_cast<const bf16x8*>(lbase + cur * 8192 + rdo[kc]);
      acc = mfma_k32(af[kc], bfr, acc);
    }
    int colb = nt * 16 + lr;
    float bias = bo[colb];
    #pragma unroll
    for (int r = 0; r < 4; ++r) {
      int m = m0 + w * 16 + lg * 4 + r;
      out[(size_t)m * 256 + colb] = acc[r] + bias;
    }
    if (nt < 15) {
      *reinterpret_cast<int4*>(lbase + nxt * 8192 + P0) = t0;
      *reinterpret_cast<int4*>(lbase + nxt * 8192 + P1) = t1;
    }
    __syncthreads();
  }
}

extern "C" void kernel_launch(void* const* d_in, const int* in_sizes, int n_in,
                              void* d_out, int out_size, void* d_ws, size_t ws_size,
                              hipStream_t stream) {
  const float* x  = (const float*)d_in[0];
  const float* Wq = (const float*)d_in[1];
  const float* Wk = (const float*)d_in[2];
  const float* Wv = (const float*)d_in[3];
  const float* bt = (const float*)d_in[4];
  const float* Wo = (const float*)d_in[5];
  const float* bo = (const float*)d_in[6];
  float* out = (float*)d_out;
  char* ws = (char*)d_ws;
  short* WT   = (short*)ws;                          // 4 x 65536 shorts = 512 KB
  short* Qs   = (short*)(ws + 512 * 1024);           // 8 MB each
  short* Ks   = Qs + 4194304;
  short* Vts  = Ks + 4194304;
  short* aout = Vts + 4194304;
  float* Tg   = (float*)(ws + 512 * 1024 + 4ull * 8388608);  // 8x4096 f32 = 128 KB

  k_prep<<<1152, 256, 0, stream>>>(Wq, Wk, Wv, Wo, WT, bt, Tg);
  k_qkv<<<dim3(256, 3), 256, 0, stream>>>(x, WT, Qs, Ks, Vts);
  k_attn<<<1024, 512, 0, stream>>>(Qs, Ks, Vts, Tg, aout);
  k_outproj<<<256, 256, 0, stream>>>(aout, WT + 3 * 65536, bo, out);
}

// Round 12
// 77.982 us; speedup vs baseline: 1.6161x; 1.0126x over previous
//
#include <hip/hip_runtime.h>

// Swin-style attention: B=16, N=1024 (32x32), H=8, D=32, C=256.
// R11: (a) Q pre-scaled by scale*log2e in k_qkv; bias rides the QK MFMA as
// the C-operand -> the 16 per-iter fmaf disappear and exp2 reads the MFMA
// output directly. (b) k_attn LDS overlay: merge buffers reuse the bias-table
// space after a barrier -> 18.4KB/block (was 34.8) for more resident blocks.
// Projections: R9 W-through-dbuf-LDS (unchanged).

using f32x4  = __attribute__((ext_vector_type(4))) float;
using bf16x8 = __attribute__((ext_vector_type(8))) short;

__device__ __forceinline__ short f2bf(float f) {
  union { float f; unsigned u; } v; v.f = f;
  return (short)((v.u + 0x7FFFu + ((v.u >> 16) & 1u)) >> 16);  // RNE
}
__device__ __forceinline__ f32x4 mfma_k32(bf16x8 a, bf16x8 b, f32x4 c) {
  return __builtin_amdgcn_mfma_f32_16x16x32_bf16(a, b, c, 0, 0, 0);
}
__device__ __forceinline__ int cvt_pk_bf16(float lo, float hi) {
  int r;
  asm("v_cvt_pk_bf16_f32 %0, %1, %2" : "=v"(r) : "v"(lo), "v"(hi));
  return r;
}
// bias fragment: C[r] = row[p - r]
__device__ __forceinline__ f32x4 ldb(const float* __restrict__ row, int p) {
  f32x4 v;
  v[0] = row[p]; v[1] = row[p - 1]; v[2] = row[p - 2]; v[3] = row[p - 3];
  return v;
}

#define CSQ 0.25500526817f  /* (1/sqrt(32)) * log2(e) */

// ------- kernel 0: 4 weight transposes (bf16) + bias table prep, one launch ----
__global__ __launch_bounds__(256) void k_prep(const float* __restrict__ Wq,
    const float* __restrict__ Wk, const float* __restrict__ Wv,
    const float* __restrict__ Wo, short* __restrict__ WT,
    const float* __restrict__ bt, float* __restrict__ Tg) {
  int bx = blockIdx.x;
  if (bx < 1024) {
    int wid = bx >> 8, n = bx & 255, k = threadIdx.x;
    const float* W = wid == 0 ? Wq : wid == 1 ? Wk : wid == 2 ? Wv : Wo;
    WT[wid * 65536 + n * 256 + k] = f2bf(W[k * 256 + n]);
  } else {
    int idx = (bx - 1024) * 256 + threadIdx.x;  // 128 x 256 = 8 x 4096
    int h = idx >> 12, i = idx & 4095;
    if (i < 3969) Tg[idx] = bt[i * 8 + h] * 1.4426950408889634f;
  }
}

// ---------------- kernel 1: QKV projection, W via dbuf LDS (R9) ----------------
// Q output pre-scaled by CSQ (folded into attention's QK MFMA).
__global__ __launch_bounds__(256) void k_qkv(const float* __restrict__ x,
    const short* __restrict__ WT,
    short* __restrict__ Q, short* __restrict__ K, short* __restrict__ Vt) {
  __shared__ short Wlds[2][4096];  // 2 x 8KB
  char* lbase = (char*)Wlds;
  const int tid = threadIdx.x;
  const int w = tid >> 6, l = tid & 63, lr = l & 15, lg = l >> 4;
  const int m0 = blockIdx.x * 64;
  const int wi = blockIdx.y;
  const char* Wb = (const char*)(WT + wi * 65536);
  const float* xrow = x + (size_t)(m0 + w * 16 + lr) * 256;
  bf16x8 af[8];
  #pragma unroll
  for (int kc = 0; kc < 8; ++kc) {
    float4 a = *reinterpret_cast<const float4*>(xrow + kc * 32 + lg * 8);
    float4 c = *reinterpret_cast<const float4*>(xrow + kc * 32 + lg * 8 + 4);
    union { int i4[4]; bf16x8 v; } u;
    u.i4[0] = cvt_pk_bf16(a.x, a.y);
    u.i4[1] = cvt_pk_bf16(a.z, a.w);
    u.i4[2] = cvt_pk_bf16(c.x, c.y);
    u.i4[3] = cvt_pk_bf16(c.z, c.w);
    af[kc] = u.v;
  }
  const int Lb0 = tid * 16, Lb1 = 4096 + tid * 16;
  const int P0 = Lb0 ^ (((Lb0 >> 9) & 7) << 4);
  const int P1 = Lb1 ^ (((Lb1 >> 9) & 7) << 4);
  int rdo[8];
  #pragma unroll
  for (int kc = 0; kc < 8; ++kc) {
    int Lg = lr * 512 + kc * 64 + lg * 16;
    rdo[kc] = Lg ^ ((lr & 7) << 4);
  }
  {
    int4 s0 = *reinterpret_cast<const int4*>(Wb + Lb0);
    int4 s1 = *reinterpret_cast<const int4*>(Wb + Lb1);
    *reinterpret_cast<int4*>(lbase + P0) = s0;
    *reinterpret_cast<int4*>(lbase + P1) = s1;
  }
  __syncthreads();
  #pragma unroll 2
  for (int nt = 0; nt < 16; ++nt) {
    const int cur = nt & 1, nxt = cur ^ 1;
    int4 t0, t1;
    if (nt < 15) {
      t0 = *reinterpret_cast<const int4*>(Wb + (nt + 1) * 8192 + Lb0);
      t1 = *reinterpret_cast<const int4*>(Wb + (nt + 1) * 8192 + Lb1);
    }
    f32x4 acc = {0.f, 0.f, 0.f, 0.f};
    #pragma unroll
    for (int kc = 0; kc < 8; ++kc) {
      bf16x8 bfr = *reinterpret_cast<const bf16x8*>(lbase + cur * 8192 + rdo[kc]);
      acc = mfma_k32(af[kc], bfr, acc);
    }
    int colb = nt * 16 + lr;
    int h = colb >> 5, d = colb & 31;
    if (wi == 2) {
      int m = m0 + w * 16 + lg * 4;
      int b = m >> 10, n0 = m & 1023;
      int js = n0 >> 5;
      int lgv = (n0 & 15) >> 2, hi = (n0 >> 4) & 1;
      int jp = lgv * 8 + hi * 4;
      short4 vv;
      vv.x = f2bf(acc[0]); vv.y = f2bf(acc[1]);
      vv.z = f2bf(acc[2]); vv.w = f2bf(acc[3]);
      *reinterpret_cast<short4*>(
          &Vt[(((size_t)(b * 8 + h) * 32 + js) << 10) + d * 32 + jp]) = vv;
    } else {
      #pragma unroll
      for (int r = 0; r < 4; ++r) {
        int m = m0 + w * 16 + lg * 4 + r;
        int b = m >> 10, n = m & 1023;
        short val = (wi == 0) ? f2bf(acc[r] * CSQ) : f2bf(acc[r]);
        if (wi == 0)
          Q[((size_t)(b * 8 + h) * 1024 + n) * 32 + d] = val;
        else
          K[((size_t)(b * 8 + h) * 1024 + n) * 32 + d] = val;
      }
    }
    if (nt < 15) {
      *reinterpret_cast<int4*>(lbase + nxt * 8192 + P0) = t0;
      *reinterpret_cast<int4*>(lbase + nxt * 8192 + P1) = t1;
    }
    __syncthreads();
  }
}

// ------- kernel 2: flash attention, 8 waves, j-split, bias-as-C-init ----------
// Block = (b, h, qt): waves 0-3 -> js 0..15, waves 4-7 -> js 16..31 of the
// same two i-tiles (rows i0a, i0a+512). S' = mfma(K, Q*CSQ, C=bias*log2e);
// p = exp2(S'). Merge buffers OVERLAY the bias table (dead after the loop).
__global__ __launch_bounds__(512) void k_attn(const short* __restrict__ Q,
    const short* __restrict__ K, const short* __restrict__ Vt,
    const float* __restrict__ Tg, short* __restrict__ aout) {
  __shared__ char smraw[18432];
  float* Tlds = (float*)smraw;                       // 3969 f32 (bias table)
  auto mO  = (float(*)[4][4][64])smraw;              // [w][slot][r][l] 16KB
  auto mls = (float(*)[2][64])(smraw + 16384);       // [w][tile][l]   2KB
  const int tid = threadIdx.x, bid = blockIdx.x;
  const int h = bid & 7, qt = (bid >> 3) & 7, b = bid >> 6;
  const float* Th = Tg + (h << 12);
  for (int t = tid; t < 3969; t += 512) Tlds[t] = Th[t];
  __syncthreads();
  const int wg = tid >> 6, l = tid & 63, lr = l & 15, lg = l >> 4;
  const int w = wg & 3, jh = wg >> 2;
  const size_t hoff = (size_t)(b * 8 + h) << 15;
  const short* Qh = Q + hoff;
  const short* Kh = K + hoff;
  const short* Vh = Vt + hoff;
  const int ita = qt * 4 + w;          // 0..31
  const int i0a = ita * 16;            // rows 0..511
  const int i0b = i0a + 512;           // rows 512..1023 (same x-parity)
  const int yia = ita >> 1;
  const int pbase = ((ita & 1) << 4) + lr - lg * 4 + 31;
  bf16x8 qfa = *reinterpret_cast<const bf16x8*>(&Qh[(i0a + lr) * 32 + lg * 8]);
  bf16x8 qfb = *reinterpret_cast<const bf16x8*>(&Qh[(i0b + lr) * 32 + lg * 8]);
  f32x4 oa0 = {0.f,0.f,0.f,0.f}, oa1 = {0.f,0.f,0.f,0.f};
  f32x4 ob0 = {0.f,0.f,0.f,0.f}, ob1 = {0.f,0.f,0.f,0.f};
  float lsa = 0.f, lsb = 0.f;
  const int koff0 = lr * 32 + lg * 8, koff1 = (16 + lr) * 32 + lg * 8;
  const int js0 = jh * 16, jsE = js0 + 16;
  bf16x8 kf0 = *reinterpret_cast<const bf16x8*>(&Kh[(js0 << 10) + koff0]);
  bf16x8 kf1 = *reinterpret_cast<const bf16x8*>(&Kh[(js0 << 10) + koff1]);
  bf16x8 vf0 = *reinterpret_cast<const bf16x8*>(&Vh[(js0 << 10) + koff0]);
  bf16x8 vf1 = *reinterpret_cast<const bf16x8*>(&Vh[(js0 << 10) + koff1]);
  #pragma unroll 2
  for (int js = js0; js < jsE; ++js) {
    const int jn = (js + 1 < jsE) ? js + 1 : js;  // last iter: redundant reload
    bf16x8 nkf0 = *reinterpret_cast<const bf16x8*>(&Kh[(jn << 10) + koff0]);
    bf16x8 nkf1 = *reinterpret_cast<const bf16x8*>(&Kh[(jn << 10) + koff1]);
    bf16x8 nvf0 = *reinterpret_cast<const bf16x8*>(&Vh[(jn << 10) + koff0]);
    bf16x8 nvf1 = *reinterpret_cast<const bf16x8*>(&Vh[(jn << 10) + koff1]);
    const float* TrowA = &Tlds[(yia - js + 31) * 63];
    f32x4 bA0 = ldb(TrowA, pbase);
    f32x4 bA1 = ldb(TrowA, pbase - 16);
    f32x4 bB0 = ldb(TrowA + 1008, pbase);        // TrowB = TrowA + 16*63
    f32x4 bB1 = ldb(TrowA + 1008, pbase - 16);
    f32x4 sa0 = mfma_k32(kf0, qfa, bA0);  // score*CSQ + bias*l2e, row i0a+lr
    f32x4 sa1 = mfma_k32(kf1, qfa, bA1);
    f32x4 sb0 = mfma_k32(kf0, qfb, bB0);  // row i0b+lr
    f32x4 sb1 = mfma_k32(kf1, qfb, bB1);
    float pa0[4], pa1[4], pb0[4], pb1[4];
    #pragma unroll
    for (int r = 0; r < 4; ++r) {
      pa0[r] = __builtin_amdgcn_exp2f(sa0[r]);
      pa1[r] = __builtin_amdgcn_exp2f(sa1[r]);
      pb0[r] = __builtin_amdgcn_exp2f(sb0[r]);
      pb1[r] = __builtin_amdgcn_exp2f(sb1[r]);
      lsa += pa0[r] + pa1[r];
      lsb += pb0[r] + pb1[r];
    }
    union { int i4[4]; bf16x8 v; } pka, pkb;
    pka.i4[0] = cvt_pk_bf16(pa0[0], pa0[1]);
    pka.i4[1] = cvt_pk_bf16(pa0[2], pa0[3]);
    pka.i4[2] = cvt_pk_bf16(pa1[0], pa1[1]);
    pka.i4[3] = cvt_pk_bf16(pa1[2], pa1[3]);
    pkb.i4[0] = cvt_pk_bf16(pb0[0], pb0[1]);
    pkb.i4[1] = cvt_pk_bf16(pb0[2], pb0[3]);
    pkb.i4[2] = cvt_pk_bf16(pb1[0], pb1[1]);
    pkb.i4[3] = cvt_pk_bf16(pb1[2], pb1[3]);
    oa0 = mfma_k32(pka.v, vf0, oa0);  // O[i0a+lg*4+r][d=lr]
    oa1 = mfma_k32(pka.v, vf1, oa1);  // O[i0a+..][d=16+lr]
    ob0 = mfma_k32(pkb.v, vf0, ob0);
    ob1 = mfma_k32(pkb.v, vf1, ob1);
    kf0 = nkf0; kf1 = nkf1; vf0 = nvf0; vf1 = nvf1;
  }
  // all waves done with Tlds before merge buffers overwrite it
  __syncthreads();
  if (jh == 1) {
    #pragma unroll
    for (int r = 0; r < 4; ++r) {
      mO[w][0][r][l] = oa0[r];
      mO[w][1][r][l] = oa1[r];
      mO[w][2][r][l] = ob0[r];
      mO[w][3][r][l] = ob1[r];
    }
    mls[w][0][l] = lsa;
    mls[w][1][l] = lsb;
  }
  __syncthreads();
  if (jh == 0) {
    #pragma unroll
    for (int r = 0; r < 4; ++r) {
      oa0[r] += mO[w][0][r][l];
      oa1[r] += mO[w][1][r][l];
      ob0[r] += mO[w][2][r][l];
      ob1[r] += mO[w][3][r][l];
    }
    lsa += mls[w][0][l];
    lsb += mls[w][1][l];
    {
      float s = lsa + __shfl_xor(lsa, 16);
      s += __shfl_xor(s, 32);
      float inv = 1.0f / s;
      #pragma unroll
      for (int r = 0; r < 4; ++r) {
        float invr = __shfl(inv, lg * 4 + r);
        int n = i0a + lg * 4 + r;
        size_t base = ((size_t)b << 18) + (size_t)n * 256 + h * 32;
        aout[base + lr]      = f2bf(oa0[r] * invr);
        aout[base + 16 + lr] = f2bf(oa1[r] * invr);
      }
      s = lsb + __shfl_xor(lsb, 16);
      s += __shfl_xor(s, 32);
      inv = 1.0f / s;
      #pragma unroll
      for (int r = 0; r < 4; ++r) {
        float invr = __shfl(inv, lg * 4 + r);
        int n = i0b + lg * 4 + r;
        size_t base = ((size_t)b << 18) + (size_t)n * 256 + h * 32;
        aout[base + lr]      = f2bf(ob0[r] * invr);
        aout[base + 16 + lr] = f2bf(ob1[r] * invr);
      }
    }
  }
}

// ---------------- kernel 3: output projection, W via dbuf LDS (R9) -------------
__global__ __launch_bounds__(256) void k_outproj(const short* __restrict__ aout,
    const short* __restrict__ WoT, const float* __restrict__ bo,
    float* __restrict__ out) {
  __shared__ short Wlds[2][4096];
  char* lbase = (char*)Wlds;
  const int tid = threadIdx.x;
  const int w = tid >> 6, l = tid & 63, lr = l & 15, lg = l >> 4;
  const int m0 = blockIdx.x * 64;
  const char* Wb = (const char*)WoT;
  const short* arow = aout + (size_t)(m0 + w * 16 + lr) * 256;
  bf16x8 af[8];
  #pragma unroll
  for (int kc = 0; kc < 8; ++kc)
    af[kc] = *reinterpret_cast<const bf16x8*>(arow + kc * 32 + lg * 8);
  const int Lb0 = tid * 16, Lb1 = 4096 + tid * 16;
  const int P0 = Lb0 ^ (((Lb0 >> 9) & 7) << 4);
  const int P1 = Lb1 ^ (((Lb1 >> 9) & 7) << 4);
  int rdo[8];
  #pragma unroll
  for (int kc = 0; kc < 8; ++kc) {
    int Lg = lr * 512 + kc * 64 + lg * 16;
    rdo[kc] = Lg ^ ((lr & 7) << 4);
  }
  {
    int4 s0 = *reinterpret_cast<const int4*>(Wb + Lb0);
    int4 s1 = *reinterpret_cast<const int4*>(Wb + Lb1);
    *reinterpret_cast<int4*>(lbase + P0) = s0;
    *reinterpret_cast<int4*>(lbase + P1) = s1;
  }
  __syncthreads();
  #pragma unroll 2
  for (int nt = 0; nt < 16; ++nt) {
    const int cur = nt & 1, nxt = cur ^ 1;
    int4 t0, t1;
    if (nt < 15) {
      t0 = *reinterpret_cast<const int4*>(Wb + (nt + 1) * 8192 + Lb0);
      t1 = *reinterpret_cast<const int4*>(Wb + (nt + 1) * 8192 + Lb1);
    }
    f32x4 acc = {0.f, 0.f, 0.f, 0.f};
    #pragma unroll
    for (int kc = 0; kc < 8; ++kc) {
      bf16x8 bfr = *reinterpret_cast<const bf16x8*>(lbase + cur * 8192 + rdo[kc]);
      acc = mfma_k32(af[kc], bfr, acc);
    }
    int colb = nt * 16 + lr;
    float bias = bo[colb];
    #pragma unroll
    for (int r = 0; r < 4; ++r) {
      int m = m0 + w * 16 + lg * 4 + r;
      out[(size_t)m * 256 + colb] = acc[r] + bias;
    }
    if (nt < 15) {
      *reinterpret_cast<int4*>(lbase + nxt * 8192 + P0) = t0;
      *reinterpret_cast<int4*>(lbase + nxt * 8192 + P1) = t1;
    }
    __syncthreads();
  }
}

extern "C" void kernel_launch(void* const* d_in, const int* in_sizes, int n_in,
                              void* d_out, int out_size, void* d_ws, size_t ws_size,
                              hipStream_t stream) {
  const float* x  = (const float*)d_in[0];
  const float* Wq = (const float*)d_in[1];
  const float* Wk = (const float*)d_in[2];
  const float* Wv = (const float*)d_in[3];
  const float* bt = (const float*)d_in[4];
  const float* Wo = (const float*)d_in[5];
  const float* bo = (const float*)d_in[6];
  float* out = (float*)d_out;
  char* ws = (char*)d_ws;
  short* WT   = (short*)ws;                          // 4 x 65536 shorts = 512 KB
  short* Qs   = (short*)(ws + 512 * 1024);           // 8 MB each
  short* Ks   = Qs + 4194304;
  short* Vts  = Ks + 4194304;
  short* aout = Vts + 4194304;
  float* Tg   = (float*)(ws + 512 * 1024 + 4ull * 8388608);  // 8x4096 f32 = 128 KB

  k_prep<<<1152, 256, 0, stream>>>(Wq, Wk, Wv, Wo, WT, bt, Tg);
  k_qkv<<<dim3(256, 3), 256, 0, stream>>>(x, WT, Qs, Ks, Vts);
  k_attn<<<1024, 512, 0, stream>>>(Qs, Ks, Vts, Tg, aout);
  k_outproj<<<256, 256, 0, stream>>>(aout, WT + 3 * 65536, bo, out);
}

// Round 13
// 75.322 us; speedup vs baseline: 1.6731x; 1.0353x over previous
//
#include <hip/hip_runtime.h>

// Swin-style attention: B=16, N=1024 (32x32), H=8, D=32, C=256.
// R12: (a) k_attn K/V register prefetch depth 2 (covers ~300cyc L2 latency;
// depth 1 left vmcnt stalls = the non-issue half of the time); (b) k_prep
// transpose via LDS tiles (old version read W at stride-1KB/lane, 16x HBM
// overfetch); (c) k_outproj split into 2 column-halves (2 blocks/CU).
// Bias rides QK MFMA C-operand (R11); V fragment-subtiled (R6); j-split (R10).

using f32x4  = __attribute__((ext_vector_type(4))) float;
using bf16x8 = __attribute__((ext_vector_type(8))) short;

__device__ __forceinline__ short f2bf(float f) {
  union { float f; unsigned u; } v; v.f = f;
  return (short)((v.u + 0x7FFFu + ((v.u >> 16) & 1u)) >> 16);  // RNE
}
__device__ __forceinline__ f32x4 mfma_k32(bf16x8 a, bf16x8 b, f32x4 c) {
  return __builtin_amdgcn_mfma_f32_16x16x32_bf16(a, b, c, 0, 0, 0);
}
__device__ __forceinline__ int cvt_pk_bf16(float lo, float hi) {
  int r;
  asm("v_cvt_pk_bf16_f32 %0, %1, %2" : "=v"(r) : "v"(lo), "v"(hi));
  return r;
}
// bias fragment: C[r] = row[p - r]
__device__ __forceinline__ f32x4 ldb(const float* __restrict__ row, int p) {
  f32x4 v;
  v[0] = row[p]; v[1] = row[p - 1]; v[2] = row[p - 2]; v[3] = row[p - 3];
  return v;
}

#define CSQ 0.25500526817f  /* (1/sqrt(32)) * log2(e) */

// ------- kernel 0: weight transposes (LDS-tiled, coalesced) + bias prep -------
// blocks [0,64): 4 matrices x 16 (64x64) tiles; blocks [64,192): bias table.
__global__ __launch_bounds__(256) void k_prep(const float* __restrict__ Wq,
    const float* __restrict__ Wk, const float* __restrict__ Wv,
    const float* __restrict__ Wo, short* __restrict__ WT,
    const float* __restrict__ bt, float* __restrict__ Tg) {
  int bx = blockIdx.x;
  if (bx < 64) {
    __shared__ float tile[64][65];
    int wid = bx >> 4, t = bx & 15;
    int ro0 = (t & 3) * 64, co0 = (t >> 2) * 64;  // ro = k-dim, co = n-dim
    const float* W = wid == 0 ? Wq : wid == 1 ? Wk : wid == 2 ? Wv : Wo;
    int tr = threadIdx.x >> 4, tc = threadIdx.x & 15;
    #pragma unroll
    for (int c = 0; c < 4; ++c) {
      int row = c * 16 + tr;
      float4 v = *reinterpret_cast<const float4*>(
          &W[(ro0 + row) * 256 + co0 + tc * 4]);
      tile[row][tc * 4 + 0] = v.x;
      tile[row][tc * 4 + 1] = v.y;
      tile[row][tc * 4 + 2] = v.z;
      tile[row][tc * 4 + 3] = v.w;
    }
    __syncthreads();
    #pragma unroll
    for (int c = 0; c < 4; ++c) {
      int orow = c * 16 + tr;  // col within tile = output n
      short4 s;
      s.x = f2bf(tile[tc * 4 + 0][orow]);
      s.y = f2bf(tile[tc * 4 + 1][orow]);
      s.z = f2bf(tile[tc * 4 + 2][orow]);
      s.w = f2bf(tile[tc * 4 + 3][orow]);
      *reinterpret_cast<short4*>(
          &WT[wid * 65536 + (co0 + orow) * 256 + ro0 + tc * 4]) = s;
    }
  } else {
    int idx = (bx - 64) * 256 + threadIdx.x;  // 128 x 256 = 8 x 4096
    int h = idx >> 12, i = idx & 4095;
    if (i < 3969) Tg[idx] = bt[i * 8 + h] * 1.4426950408889634f;
  }
}

// ---------------- kernel 1: QKV projection, W via dbuf LDS (R9) ----------------
// Q output pre-scaled by CSQ (folded into attention's QK MFMA).
__global__ __launch_bounds__(256) void k_qkv(const float* __restrict__ x,
    const short* __restrict__ WT,
    short* __restrict__ Q, short* __restrict__ K, short* __restrict__ Vt) {
  __shared__ short Wlds[2][4096];  // 2 x 8KB
  char* lbase = (char*)Wlds;
  const int tid = threadIdx.x;
  const int w = tid >> 6, l = tid & 63, lr = l & 15, lg = l >> 4;
  const int m0 = blockIdx.x * 64;
  const int wi = blockIdx.y;
  const char* Wb = (const char*)(WT + wi * 65536);
  const float* xrow = x + (size_t)(m0 + w * 16 + lr) * 256;
  bf16x8 af[8];
  #pragma unroll
  for (int kc = 0; kc < 8; ++kc) {
    float4 a = *reinterpret_cast<const float4*>(xrow + kc * 32 + lg * 8);
    float4 c = *reinterpret_cast<const float4*>(xrow + kc * 32 + lg * 8 + 4);
    union { int i4[4]; bf16x8 v; } u;
    u.i4[0] = cvt_pk_bf16(a.x, a.y);
    u.i4[1] = cvt_pk_bf16(a.z, a.w);
    u.i4[2] = cvt_pk_bf16(c.x, c.y);
    u.i4[3] = cvt_pk_bf16(c.z, c.w);
    af[kc] = u.v;
  }
  const int Lb0 = tid * 16, Lb1 = 4096 + tid * 16;
  const int P0 = Lb0 ^ (((Lb0 >> 9) & 7) << 4);
  const int P1 = Lb1 ^ (((Lb1 >> 9) & 7) << 4);
  int rdo[8];
  #pragma unroll
  for (int kc = 0; kc < 8; ++kc) {
    int Lg = lr * 512 + kc * 64 + lg * 16;
    rdo[kc] = Lg ^ ((lr & 7) << 4);
  }
  {
    int4 s0 = *reinterpret_cast<const int4*>(Wb + Lb0);
    int4 s1 = *reinterpret_cast<const int4*>(Wb + Lb1);
    *reinterpret_cast<int4*>(lbase + P0) = s0;
    *reinterpret_cast<int4*>(lbase + P1) = s1;
  }
  __syncthreads();
  #pragma unroll 2
  for (int nt = 0; nt < 16; ++nt) {
    const int cur = nt & 1, nxt = cur ^ 1;
    int4 t0, t1;
    if (nt < 15) {
      t0 = *reinterpret_cast<const int4*>(Wb + (nt + 1) * 8192 + Lb0);
      t1 = *reinterpret_cast<const int4*>(Wb + (nt + 1) * 8192 + Lb1);
    }
    f32x4 acc = {0.f, 0.f, 0.f, 0.f};
    #pragma unroll
    for (int kc = 0; kc < 8; ++kc) {
      bf16x8 bfr = *reinterpret_cast<const bf16x8*>(lbase + cur * 8192 + rdo[kc]);
      acc = mfma_k32(af[kc], bfr, acc);
    }
    int colb = nt * 16 + lr;
    int h = colb >> 5, d = colb & 31;
    if (wi == 2) {
      int m = m0 + w * 16 + lg * 4;
      int b = m >> 10, n0 = m & 1023;
      int js = n0 >> 5;
      int lgv = (n0 & 15) >> 2, hi = (n0 >> 4) & 1;
      int jp = lgv * 8 + hi * 4;
      short4 vv;
      vv.x = f2bf(acc[0]); vv.y = f2bf(acc[1]);
      vv.z = f2bf(acc[2]); vv.w = f2bf(acc[3]);
      *reinterpret_cast<short4*>(
          &Vt[(((size_t)(b * 8 + h) * 32 + js) << 10) + d * 32 + jp]) = vv;
    } else {
      #pragma unroll
      for (int r = 0; r < 4; ++r) {
        int m = m0 + w * 16 + lg * 4 + r;
        int b = m >> 10, n = m & 1023;
        short val = (wi == 0) ? f2bf(acc[r] * CSQ) : f2bf(acc[r]);
        if (wi == 0)
          Q[((size_t)(b * 8 + h) * 1024 + n) * 32 + d] = val;
        else
          K[((size_t)(b * 8 + h) * 1024 + n) * 32 + d] = val;
      }
    }
    if (nt < 15) {
      *reinterpret_cast<int4*>(lbase + nxt * 8192 + P0) = t0;
      *reinterpret_cast<int4*>(lbase + nxt * 8192 + P1) = t1;
    }
    __syncthreads();
  }
}

// ------- kernel 2: flash attention, 8 waves, j-split, depth-2 K/V prefetch ----
__global__ __launch_bounds__(512) void k_attn(const short* __restrict__ Q,
    const short* __restrict__ K, const short* __restrict__ Vt,
    const float* __restrict__ Tg, short* __restrict__ aout) {
  __shared__ char smraw[18432];
  float* Tlds = (float*)smraw;                       // 3969 f32 (bias table)
  auto mO  = (float(*)[4][4][64])smraw;              // [w][slot][r][l] 16KB
  auto mls = (float(*)[2][64])(smraw + 16384);       // [w][tile][l]   2KB
  const int tid = threadIdx.x, bid = blockIdx.x;
  const int h = bid & 7, qt = (bid >> 3) & 7, b = bid >> 6;
  const float* Th = Tg + (h << 12);
  for (int t = tid; t < 3969; t += 512) Tlds[t] = Th[t];
  __syncthreads();
  const int wg = tid >> 6, l = tid & 63, lr = l & 15, lg = l >> 4;
  const int w = wg & 3, jh = wg >> 2;
  const size_t hoff = (size_t)(b * 8 + h) << 15;
  const short* Qh = Q + hoff;
  const short* Kh = K + hoff;
  const short* Vh = Vt + hoff;
  const int ita = qt * 4 + w;          // 0..31
  const int i0a = ita * 16;            // rows 0..511
  const int i0b = i0a + 512;           // rows 512..1023 (same x-parity)
  const int yia = ita >> 1;
  const int pbase = ((ita & 1) << 4) + lr - lg * 4 + 31;
  bf16x8 qfa = *reinterpret_cast<const bf16x8*>(&Qh[(i0a + lr) * 32 + lg * 8]);
  bf16x8 qfb = *reinterpret_cast<const bf16x8*>(&Qh[(i0b + lr) * 32 + lg * 8]);
  f32x4 oa0 = {0.f,0.f,0.f,0.f}, oa1 = {0.f,0.f,0.f,0.f};
  f32x4 ob0 = {0.f,0.f,0.f,0.f}, ob1 = {0.f,0.f,0.f,0.f};
  float lsa = 0.f, lsb = 0.f;
  const int koff0 = lr * 32 + lg * 8, koff1 = (16 + lr) * 32 + lg * 8;
  const int js0 = jh * 16, jsE = js0 + 16;
  // depth-2 register pipeline: slots A (js), B (js+1); refill with js+2
  bf16x8 kA0 = *reinterpret_cast<const bf16x8*>(&Kh[(js0 << 10) + koff0]);
  bf16x8 kA1 = *reinterpret_cast<const bf16x8*>(&Kh[(js0 << 10) + koff1]);
  bf16x8 vA0 = *reinterpret_cast<const bf16x8*>(&Vh[(js0 << 10) + koff0]);
  bf16x8 vA1 = *reinterpret_cast<const bf16x8*>(&Vh[(js0 << 10) + koff1]);
  bf16x8 kB0 = *reinterpret_cast<const bf16x8*>(&Kh[((js0 + 1) << 10) + koff0]);
  bf16x8 kB1 = *reinterpret_cast<const bf16x8*>(&Kh[((js0 + 1) << 10) + koff1]);
  bf16x8 vB0 = *reinterpret_cast<const bf16x8*>(&Vh[((js0 + 1) << 10) + koff0]);
  bf16x8 vB1 = *reinterpret_cast<const bf16x8*>(&Vh[((js0 + 1) << 10) + koff1]);
  #pragma unroll 2
  for (int t = 0; t < 16; ++t) {
    const int js = js0 + t;
    int jn = js + 2;
    if (jn >= jsE) jn = jsE - 1;  // tail: redundant reload, unused
    bf16x8 nk0 = *reinterpret_cast<const bf16x8*>(&Kh[(jn << 10) + koff0]);
    bf16x8 nk1 = *reinterpret_cast<const bf16x8*>(&Kh[(jn << 10) + koff1]);
    bf16x8 nv0 = *reinterpret_cast<const bf16x8*>(&Vh[(jn << 10) + koff0]);
    bf16x8 nv1 = *reinterpret_cast<const bf16x8*>(&Vh[(jn << 10) + koff1]);
    const float* TrowA = &Tlds[(yia - js + 31) * 63];
    f32x4 bA0 = ldb(TrowA, pbase);
    f32x4 bA1 = ldb(TrowA, pbase - 16);
    f32x4 bB0 = ldb(TrowA + 1008, pbase);        // TrowB = TrowA + 16*63
    f32x4 bB1 = ldb(TrowA + 1008, pbase - 16);
    f32x4 sa0 = mfma_k32(kA0, qfa, bA0);  // score*CSQ + bias*l2e, row i0a+lr
    f32x4 sa1 = mfma_k32(kA1, qfa, bA1);
    f32x4 sb0 = mfma_k32(kA0, qfb, bB0);  // row i0b+lr
    f32x4 sb1 = mfma_k32(kA1, qfb, bB1);
    float pa0[4], pa1[4], pb0[4], pb1[4];
    #pragma unroll
    for (int r = 0; r < 4; ++r) {
      pa0[r] = __builtin_amdgcn_exp2f(sa0[r]);
      pa1[r] = __builtin_amdgcn_exp2f(sa1[r]);
      pb0[r] = __builtin_amdgcn_exp2f(sb0[r]);
      pb1[r] = __builtin_amdgcn_exp2f(sb1[r]);
      lsa += pa0[r] + pa1[r];
      lsb += pb0[r] + pb1[r];
    }
    union { int i4[4]; bf16x8 v; } pka, pkb;
    pka.i4[0] = cvt_pk_bf16(pa0[0], pa0[1]);
    pka.i4[1] = cvt_pk_bf16(pa0[2], pa0[3]);
    pka.i4[2] = cvt_pk_bf16(pa1[0], pa1[1]);
    pka.i4[3] = cvt_pk_bf16(pa1[2], pa1[3]);
    pkb.i4[0] = cvt_pk_bf16(pb0[0], pb0[1]);
    pkb.i4[1] = cvt_pk_bf16(pb0[2], pb0[3]);
    pkb.i4[2] = cvt_pk_bf16(pb1[0], pb1[1]);
    pkb.i4[3] = cvt_pk_bf16(pb1[2], pb1[3]);
    oa0 = mfma_k32(pka.v, vA0, oa0);  // O[i0a+lg*4+r][d=lr]
    oa1 = mfma_k32(pka.v, vA1, oa1);  // O[i0a+..][d=16+lr]
    ob0 = mfma_k32(pkb.v, vA0, ob0);
    ob1 = mfma_k32(pkb.v, vA1, ob1);
    kA0 = kB0; kA1 = kB1; vA0 = vB0; vA1 = vB1;
    kB0 = nk0; kB1 = nk1; vB0 = nv0; vB1 = nv1;
  }
  // all waves done with Tlds before merge buffers overwrite it
  __syncthreads();
  if (jh == 1) {
    #pragma unroll
    for (int r = 0; r < 4; ++r) {
      mO[w][0][r][l] = oa0[r];
      mO[w][1][r][l] = oa1[r];
      mO[w][2][r][l] = ob0[r];
      mO[w][3][r][l] = ob1[r];
    }
    mls[w][0][l] = lsa;
    mls[w][1][l] = lsb;
  }
  __syncthreads();
  if (jh == 0) {
    #pragma unroll
    for (int r = 0; r < 4; ++r) {
      oa0[r] += mO[w][0][r][l];
      oa1[r] += mO[w][1][r][l];
      ob0[r] += mO[w][2][r][l];
      ob1[r] += mO[w][3][r][l];
    }
    lsa += mls[w][0][l];
    lsb += mls[w][1][l];
    {
      float s = lsa + __shfl_xor(lsa, 16);
      s += __shfl_xor(s, 32);
      float inv = 1.0f / s;
      #pragma unroll
      for (int r = 0; r < 4; ++r) {
        float invr = __shfl(inv, lg * 4 + r);
        int n = i0a + lg * 4 + r;
        size_t base = ((size_t)b << 18) + (size_t)n * 256 + h * 32;
        aout[base + lr]      = f2bf(oa0[r] * invr);
        aout[base + 16 + lr] = f2bf(oa1[r] * invr);
      }
      s = lsb + __shfl_xor(lsb, 16);
      s += __shfl_xor(s, 32);
      inv = 1.0f / s;
      #pragma unroll
      for (int r = 0; r < 4; ++r) {
        float invr = __shfl(inv, lg * 4 + r);
        int n = i0b + lg * 4 + r;
        size_t base = ((size_t)b << 18) + (size_t)n * 256 + h * 32;
        aout[base + lr]      = f2bf(ob0[r] * invr);
        aout[base + 16 + lr] = f2bf(ob1[r] * invr);
      }
    }
  }
}

// ------- kernel 3: output projection, W via dbuf LDS, 2-way nt split ----------
__global__ __launch_bounds__(256) void k_outproj(const short* __restrict__ aout,
    const short* __restrict__ WoT, const float* __restrict__ bo,
    float* __restrict__ out) {
  __shared__ short Wlds[2][4096];
  char* lbase = (char*)Wlds;
  const int tid = threadIdx.x;
  const int w = tid >> 6, l = tid & 63, lr = l & 15, lg = l >> 4;
  const int m0 = blockIdx.x * 64;
  const int nt0 = blockIdx.y * 8;
  const char* Wb = (const char*)WoT + nt0 * 8192;
  const short* arow = aout + (size_t)(m0 + w * 16 + lr) * 256;
  bf16x8 af[8];
  #pragma unroll
  for (int kc = 0; kc < 8; ++kc)
    af[kc] = *reinterpret_cast<const bf16x8*>(arow + kc * 32 + lg * 8);
  const int Lb0 = tid * 16, Lb1 = 4096 + tid * 16;
  const int P0 = Lb0 ^ (((Lb0 >> 9) & 7) << 4);
  const int P1 = Lb1 ^ (((Lb1 >> 9) & 7) << 4);
  int rdo[8];
  #pragma unroll
  for (int kc = 0; kc < 8; ++kc) {
    int Lg = lr * 512 + kc * 64 + lg * 16;
    rdo[kc] = Lg ^ ((lr & 7) << 4);
  }
  {
    int4 s0 = *reinterpret_cast<const int4*>(Wb + Lb0);
    int4 s1 = *reinterpret_cast<const int4*>(Wb + Lb1);
    *reinterpret_cast<int4*>(lbase + P0) = s0;
    *reinterpret_cast<int4*>(lbase + P1) = s1;
  }
  __syncthreads();
  #pragma unroll 2
  for (int t = 0; t < 8; ++t) {
    const int cur = t & 1, nxt = cur ^ 1;
    int4 t0, t1;
    if (t < 7) {
      t0 = *reinterpret_cast<const int4*>(Wb + (t + 1) * 8192 + Lb0);
      t1 = *reinterpret_cast<const int4*>(Wb + (t + 1) * 8192 + Lb1);
    }
    f32x4 acc = {0.f, 0.f, 0.f, 0.f};
    #pragma unroll
    for (int kc = 0; kc < 8; ++kc) {
      bf16x8 bfr = *reinterpret_cast<const bf16x8*>(lbase + cur * 8192 + rdo[kc]);
      acc = mfma_k32(af[kc], bfr, acc);
    }
    int colb = (nt0 + t) * 16 + lr;
    float bias = bo[colb];
    #pragma unroll
    for (int r = 0; r < 4; ++r) {
      int m = m0 + w * 16 + lg * 4 + r;
      out[(size_t)m * 256 + colb] = acc[r] + bias;
    }
    if (t < 7) {
      *reinterpret_cast<int4*>(lbase + nxt * 8192 + P0) = t0;
      *reinterpret_cast<int4*>(lbase + nxt * 8192 + P1) = t1;
    }
    __syncthreads();
  }
}

extern "C" void kernel_launch(void* const* d_in, const int* in_sizes, int n_in,
                              void* d_out, int out_size, void* d_ws, size_t ws_size,
                              hipStream_t stream) {
  const float* x  = (const float*)d_in[0];
  const float* Wq = (const float*)d_in[1];
  const float* Wk = (const float*)d_in[2];
  const float* Wv = (const float*)d_in[3];
  const float* bt = (const float*)d_in[4];
  const float* Wo = (const float*)d_in[5];
  const float* bo = (const float*)d_in[6];
  float* out = (float*)d_out;
  char* ws = (char*)d_ws;
  short* WT   = (short*)ws;                          // 4 x 65536 shorts = 512 KB
  short* Qs   = (short*)(ws + 512 * 1024);           // 8 MB each
  short* Ks   = Qs + 4194304;
  short* Vts  = Ks + 4194304;
  short* aout = Vts + 4194304;
  float* Tg   = (float*)(ws + 512 * 1024 + 4ull * 8388608);  // 8x4096 f32 = 128 KB

  k_prep<<<192, 256, 0, stream>>>(Wq, Wk, Wv, Wo, WT, bt, Tg);
  k_qkv<<<dim3(256, 3), 256, 0, stream>>>(x, WT, Qs, Ks, Vts);
  k_attn<<<1024, 512, 0, stream>>>(Qs, Ks, Vts, Tg, aout);
  k_outproj<<<dim3(256, 2), 256, 0, stream>>>(aout, WT + 3 * 65536, bo, out);
}